// Round 2
// baseline (185.502 us; speedup 1.0000x reference)
//
#include <hip/hip_runtime.h>
#include <stdint.h>

// HDC encoder, bit-packed sign-domain implementation.
// Per (b,d): ms = sum_{w<25} keys[w,d] * prod_{j<7} L[b][1+j+w][(d-(6-j)) mod 10000]
// All values are +-1 -> sign-bit domain: product=XOR, sum=popcount, out=sign.
#define DD      10000  // DIM
#define NW      313    // 32-bit words per row (ceil(10000/32))
#define RSTRIDE 320    // padded words per packed row (1280 B)
#define B_      64
#define NROWS   (B_*31) // gathered rows: channels c=1..31 per batch (c=0 unused)
#define NKEY    25      // keys[:-7]

// ---------------- kernel 1: pack sign bits (the BW kernel) ----------------
// grid = (10, NROWS+NKEY), block = 256. Lane: one float4 -> 4-bit sign nibble;
// LDS assembly -> 32 packed words per block (1024 bits).
__global__ void k_pack(const float* __restrict__ channels,
                       const float* __restrict__ keys,
                       const float* __restrict__ mt,
                       const float* __restrict__ hrt,
                       uint32_t* __restrict__ packedL,
                       uint32_t* __restrict__ packedK) {
    int row = blockIdx.y;
    const float* src;
    uint32_t* dst;
    if (row < NROWS) {
        int b = row / 31;
        int c = 1 + (row - b * 31);          // channel 1..31
        float x = channels[b * 128 + c];     // (64,4,32), only t=0 used
        const float* base;
        int idx;
        if (c < 31) {  // motion: 3000 levels over [-3,3]
            idx = (int)rintf((x + 3.0f) / 6.0f * 2999.0f);  // rintf == jnp.round
            idx = min(max(idx, 0), 2999);
            base = mt;
        } else {       // hr: 200 levels over [50,200]
            idx = (int)rintf((x - 50.0f) / 150.0f * 199.0f);
            idx = min(max(idx, 0), 199);
            base = hrt;
        }
        src = base + (size_t)idx * DD;
        dst = packedL + (size_t)row * RSTRIDE;
    } else {
        int w = row - NROWS;
        src = keys + (size_t)w * DD;
        dst = packedK + (size_t)w * RSTRIDE;
    }

    int d0 = blockIdx.x * 1024 + threadIdx.x * 4;
    uint32_t nib = 0;
    if (d0 < DD) {                            // 10000 % 4 == 0: no partial tail
        float4 v = *(const float4*)(src + d0);
        nib =  (__float_as_uint(v.x) >> 31)
            | ((__float_as_uint(v.y) >> 31) << 1)
            | ((__float_as_uint(v.z) >> 31) << 2)
            | ((__float_as_uint(v.w) >> 31) << 3);
    }
    __shared__ uint32_t nibs[256];
    nibs[threadIdx.x] = nib;
    __syncthreads();
    if (threadIdx.x < 32) {
        uint32_t wv = 0;
#pragma unroll
        for (int k = 0; k < 8; ++k) wv |= nibs[threadIdx.x * 8 + k] << (4 * k);
        dst[blockIdx.x * 32 + threadIdx.x] = wv;   // words 0..319 all written
    }
}

// ---------------- kernel 2: bit-domain n-gram bind + majority ----------------
// One thread per (b, word) = 64*313 threads; 32 outputs each.
__global__ void k_main(const uint32_t* __restrict__ packedL,
                       const uint32_t* __restrict__ packedK,
                       float* __restrict__ out) {
    int t = blockIdx.x * 256 + threadIdx.x;
    if (t >= B_ * NW) return;
    int b  = t / NW;
    int wd = t - b * NW;

    const uint32_t* base = packedL + (size_t)b * 31 * RSTRIDE;
    uint32_t cur[32], prv[32];
#pragma unroll
    for (int c = 1; c <= 31; ++c) {
        const uint32_t* r = base + (size_t)(c - 1) * RSTRIDE;
        cur[c] = r[wd];
        if (wd != 0) {
            prv[c] = r[wd - 1];
        } else {
            // ring wrap: "previous word" = bits 9968..9999
            // bit 9968 = word311 bit16; 9984..9999 = word312 bits 0..15
            prv[c] = (r[311] >> 16) | (r[312] << 16);
        }
    }

    uint32_t c0 = 0, c1 = 0, c2 = 0, c3 = 0, c4 = 0;
#pragma unroll
    for (int w = 0; w < NKEY; ++w) {
        uint32_t ng = 0;
#pragma unroll
        for (int j = 0; j < 7; ++j) {
            const int c = 1 + j + w;       // compile-time after unroll
            const int s = 6 - j;           // ring shift (bits move toward MSB)
            uint32_t r = (s != 0) ? ((cur[c] << s) | (prv[c] >> (32 - s)))
                                  : cur[c];
            ng ^= r;
        }
        uint32_t x = packedK[w * RSTRIDE + wd] ^ ng;   // sign(key*ng) per bit
        uint32_t carry = x, tt;                        // bitsliced count += x
        tt = c0 & carry; c0 ^= carry; carry = tt;
        tt = c1 & carry; c1 ^= carry; carry = tt;
        tt = c2 & carry; c2 ^= carry; carry = tt;
        tt = c3 & carry; c3 ^= carry; carry = tt;
        c4 ^= carry;
    }
    // ms = 25 - 2*count; out = +1 iff count <= 12; neg iff count >= 13
    uint32_t neg = c4 | (c3 & c2 & (c1 | c0));

    float4* o = (float4*)(out + (size_t)b * DD + (size_t)wd * 32);
    int n4 = min(8, 2500 - wd * 8);        // word 312: only 4 valid float4s
#pragma unroll
    for (int q = 0; q < 8; ++q) {
        if (q < n4) {
            float4 v;
            v.x = __uint_as_float(0x3F800000u | (((neg >> (4 * q + 0)) & 1u) << 31));
            v.y = __uint_as_float(0x3F800000u | (((neg >> (4 * q + 1)) & 1u) << 31));
            v.z = __uint_as_float(0x3F800000u | (((neg >> (4 * q + 2)) & 1u) << 31));
            v.w = __uint_as_float(0x3F800000u | (((neg >> (4 * q + 3)) & 1u) << 31));
            o[q] = v;
        }
    }
}

extern "C" void kernel_launch(void* const* d_in, const int* in_sizes, int n_in,
                              void* d_out, int out_size, void* d_ws, size_t ws_size,
                              hipStream_t stream) {
    const float* channels = (const float*)d_in[0];   // (64,4,32)
    const float* keys     = (const float*)d_in[1];   // (32,10000)
    const float* mt       = (const float*)d_in[2];   // (3000,10000)
    const float* hrt      = (const float*)d_in[3];   // (200,10000)
    float* out = (float*)d_out;                      // (64,10000)

    // ws layout: [packedL 1984*320*4 = 2.54MB][packedK 25*320*4 = 32KB]
    uint32_t* packedL = (uint32_t*)d_ws;
    uint32_t* packedK = (uint32_t*)((char*)d_ws + (size_t)NROWS * RSTRIDE * 4);

    dim3 gp(10, NROWS + NKEY);
    k_pack<<<gp, 256, 0, stream>>>(channels, keys, mt, hrt, packedL, packedK);

    k_main<<<(B_ * NW + 255) / 256, 256, 0, stream>>>(packedL, packedK, out);
}